// Round 7
// baseline (141.478 us; speedup 1.0000x reference)
//
#include <hip/hip_runtime.h>
#include <math.h>

#define DIM 384
#define NH 6
#define DH 64
#define B_ 2
#define S_ 2048
#define EPS 1e-6f
#define LN_EPS 1e-5f
#define G3 (3*DIM)   // 1152
#define LOG2E 1.44269504f
#define KSTR 72      // LDS row stride (ushort): 144 B -> 4-bank rotate/row
#define NT (S_/64)   // 32 q-tiles per (b,h)
#define NSPLIT 4     // t-range splits per q-tile (flash-decoding)
#define NBH (B_*NH)  // 12

typedef __attribute__((ext_vector_type(8))) short bf16x8;
typedef __attribute__((ext_vector_type(4))) short bf16x4;
typedef __attribute__((ext_vector_type(4))) float f32x4;

__device__ __forceinline__ unsigned short f2bf(float f){
    unsigned int u = __float_as_uint(f);
    u += 0x7fff + ((u >> 16) & 1);   // round-to-nearest-even
    return (unsigned short)(u >> 16);
}

__device__ __forceinline__ float logsig(float x){
    return fminf(x, 0.f) - log1pf(expf(-fabsf(x)));
}

// ---------------- Kernel 1: gate projections (float4-vectorized) -------------
// One wave per (b,s). Round-6 post-mortem: the scalar version issued ~450
// global_load_dword per wave (VMEM-issue bound); float4 for x and both weight
// rows cuts that to ~58 VMEM instructions for the same FLOPs.
__global__ __launch_bounds__(256) void gates_kernel(
    const float* __restrict__ q, const float* __restrict__ k, const float* __restrict__ v,
    const float* __restrict__ iw, const float* __restrict__ ib,
    const float* __restrict__ fw, const float* __restrict__ fb,
    float* __restrict__ ig_out, float* __restrict__ lf_out) {
    int wave = (blockIdx.x * 256 + threadIdx.x) >> 6;
    int lane = threadIdx.x & 63;
    int b = wave / S_, s = wave % S_;
    size_t base = ((size_t)b * S_ + s) * DIM;
    float aI[NH], aF[NH];
    #pragma unroll
    for (int h = 0; h < NH; h++){ aI[h] = 0.f; aF[h] = 0.f; }
    // 288 float4 groups over [q|k|v]; each group lies entirely in one tensor
    for (int g = lane; g < G3/4; g += 64) {
        int e = g * 4;
        float4 x4;
        if (e < DIM)        x4 = *(const float4*)(q + base + e);
        else if (e < 2*DIM) x4 = *(const float4*)(k + base + e - DIM);
        else                x4 = *(const float4*)(v + base + e - 2*DIM);
        #pragma unroll
        for (int h = 0; h < NH; h++){
            float4 wi = *(const float4*)(iw + h*G3 + e);
            float4 wf = *(const float4*)(fw + h*G3 + e);
            aI[h] = fmaf(x4.x, wi.x, fmaf(x4.y, wi.y, fmaf(x4.z, wi.z, fmaf(x4.w, wi.w, aI[h]))));
            aF[h] = fmaf(x4.x, wf.x, fmaf(x4.y, wf.y, fmaf(x4.z, wf.z, fmaf(x4.w, wf.w, aF[h]))));
        }
    }
    #pragma unroll
    for (int h = 0; h < NH; h++){
        #pragma unroll
        for (int off = 32; off >= 1; off >>= 1){
            aI[h] += __shfl_xor(aI[h], off, 64);
            aF[h] += __shfl_xor(aF[h], off, 64);
        }
    }
    if (lane == 0) {
        #pragma unroll
        for (int h = 0; h < NH; h++){
            ig_out[((size_t)b*NH + h)*S_ + s] = aI[h] + ib[h];
            lf_out[((size_t)b*NH + h)*S_ + s] = logsig(aF[h] + fb[h]);
        }
    }
}

// ---------------- Kernel 2: cumsum of log-sigmoid(fgate) ----------------
__global__ __launch_bounds__(256) void scan_kernel(const float* __restrict__ lf,
                                                   float* __restrict__ cum){
    int bh = blockIdx.x;
    const float* src = lf + (size_t)bh * S_;
    float* dst = cum + (size_t)bh * S_;
    int tid = threadIdx.x;
    float loc[8];
    float run = 0.f;
    #pragma unroll
    for (int j = 0; j < 8; j++){ run += src[tid*8 + j]; loc[j] = run; }
    __shared__ float sm[256];
    sm[tid] = run;
    __syncthreads();
    float total = run;
    for (int off = 1; off < 256; off <<= 1){
        float vv = (tid >= off) ? sm[tid - off] : 0.f;
        __syncthreads();
        sm[tid] += vv;
        __syncthreads();
    }
    float excl = sm[tid] - total;
    #pragma unroll
    for (int j = 0; j < 8; j++) dst[tid*8 + j] = excl + loc[j];
}

// ---------------- Kernel 3a: split-T partial flash-mLSTM ----------------
// Each q-tile's causal t-range is cut into NSPLIT=4 splits of L=ceil((st+1)/4)
// t-tiles; one 4-wave block per split (<=8 iterations serial critical path,
// was 32). Partials (m-hat, l-hat, O-hat 64x64 fp32) go to workspace.
// Transpose-free S^T formulation (rounds 2-4 tripwire post-mortem).
__global__ __launch_bounds__(256) void mlstm_part(
    const float* __restrict__ q, const float* __restrict__ k, const float* __restrict__ v,
    const float* __restrict__ ig, const float* __restrict__ cum,
    float* __restrict__ pO, float* __restrict__ pM, float* __restrict__ pL) {
    int lin = blockIdx.x;            // 0..NBH*NT*NSPLIT-1
    int sp  = lin / NBH;             // 0..127: split-slot, longest q-tiles first
    int bh  = lin % NBH;
    int st  = (NT - 1) - (sp >> 2);
    int c   = sp & 3;
    int L   = (st + 4) >> 2;         // ceil((st+1)/4)
    int tb0 = c * L;
    int tb1 = min((c + 1) * L, st + 1);
    int pblk = lin;
    int tid = threadIdx.x;

    if (tb0 >= tb1){                 // empty split: neutral partial, exit
        if (tid < 64){ pM[pblk*64 + tid] = -INFINITY; pL[pblk*64 + tid] = 0.f; }
        return;
    }

    __shared__ unsigned short kt[64*KSTR];   // K row-major: kt[t][d]
    __shared__ unsigned short vt[64*KSTR];   // V transposed: vt[d][t]
    __shared__ float cumL[64];
    __shared__ float igL[64];

    int b = bh / NH, h = bh % NH;
    int s0 = st * 64;
    int wv   = tid >> 6;
    int lane = tid & 63;
    int lq   = lane & 15;
    int quad = lane >> 4;

    const float* qbase = q + (size_t)b*S_*DIM + h*DH;
    const float* kbase = k + (size_t)b*S_*DIM + h*DH;
    const float* vbase = v + (size_t)b*S_*DIM + h*DH;
    const float* igb = ig + (size_t)bh*S_;
    const float* cmb = cum + (size_t)bh*S_;

    int s_glob = s0 + 16*wv + lq;    // s-row this lane's softmax state tracks

    // Q as B-operand fragments: B[n=lq][k=quad*8+j], x0.125
    bf16x8 qf[2];
    {
        const float* qr = qbase + (size_t)s_glob*DIM;
        #pragma unroll
        for (int ks = 0; ks < 2; ks++){
            float4 a = *(const float4*)(qr + 32*ks + 8*quad);
            float4 cc = *(const float4*)(qr + 32*ks + 8*quad + 4);
            bf16x8 t;
            t[0]=(short)f2bf(a.x*0.125f); t[1]=(short)f2bf(a.y*0.125f);
            t[2]=(short)f2bf(a.z*0.125f); t[3]=(short)f2bf(a.w*0.125f);
            t[4]=(short)f2bf(cc.x*0.125f); t[5]=(short)f2bf(cc.y*0.125f);
            t[6]=(short)f2bf(cc.z*0.125f); t[7]=(short)f2bf(cc.w*0.125f);
            qf[ks] = t;
        }
    }

    float cq  = cmb[s_glob];
    float m_s = -INFINITY, b_s = 0.f;
    f32x4 oacc[4];                   // O C-layout: row s=4quad+r, col d=16cg+lq
    #pragma unroll
    for (int cg = 0; cg < 4; cg++) oacc[cg] = (f32x4){0.f,0.f,0.f,0.f};

    int srow[4], scol[4];
    #pragma unroll
    for (int i = 0; i < 4; i++){
        int idx = tid + 256*i;
        srow[i] = idx >> 4;
        scol[i] = (idx & 15) << 2;
    }

    float4 kreg[4], vreg[4];
    {
        const float* kb = kbase + (size_t)(tb0*64)*DIM;
        const float* vb = vbase + (size_t)(tb0*64)*DIM;
        #pragma unroll
        for (int i = 0; i < 4; i++){
            kreg[i] = *(const float4*)(kb + (size_t)srow[i]*DIM + scol[i]);
            vreg[i] = *(const float4*)(vb + (size_t)srow[i]*DIM + scol[i]);
        }
    }

    for (int t0 = tb0*64; t0 < tb1*64; t0 += 64){
        __syncthreads();   // B1: prev iteration done reading kt/vt/cumL/igL
        #pragma unroll
        for (int i = 0; i < 4; i++){
            int r = srow[i], cc = scol[i];
            ushort4 kk; kk.x=f2bf(kreg[i].x); kk.y=f2bf(kreg[i].y);
            kk.z=f2bf(kreg[i].z); kk.w=f2bf(kreg[i].w);
            *(ushort4*)&kt[r*KSTR + cc] = kk;
            vt[(cc+0)*KSTR + r] = f2bf(vreg[i].x);
            vt[(cc+1)*KSTR + r] = f2bf(vreg[i].y);
            vt[(cc+2)*KSTR + r] = f2bf(vreg[i].z);
            vt[(cc+3)*KSTR + r] = f2bf(vreg[i].w);
        }
        if (tid < 64){ cumL[tid] = cmb[t0 + tid]; igL[tid] = igb[t0 + tid]; }
        __syncthreads();   // B2: tiles staged

        // prefetch next tile of this split (overlaps compute)
        if (t0 + 64 < tb1*64){
            const float* kb = kbase + (size_t)(t0 + 64)*DIM;
            const float* vb = vbase + (size_t)(t0 + 64)*DIM;
            #pragma unroll
            for (int i = 0; i < 4; i++){
                kreg[i] = *(const float4*)(kb + (size_t)srow[i]*DIM + scol[i]);
                vreg[i] = *(const float4*)(vb + (size_t)srow[i]*DIM + scol[i]);
            }
        }

        // ---- matmul1: S^T blocks ----
        f32x4 st4[4];
        #pragma unroll
        for (int tb = 0; tb < 4; tb++) st4[tb] = (f32x4){0.f,0.f,0.f,0.f};
        #pragma unroll
        for (int ks = 0; ks < 2; ks++){
            #pragma unroll
            for (int tb = 0; tb < 4; tb++){
                bf16x8 af = *(const bf16x8*)&kt[(16*tb + lq)*KSTR + 32*ks + 8*quad];
                st4[tb] = __builtin_amdgcn_mfma_f32_16x16x32_bf16(af, qf[ks], st4[tb], 0, 0, 0);
            }
        }

        // ---- decay + causal mask + online softmax (per s=lq) ----
        bool diag = (t0 == s0);
        float dv[4][4];
        float pmax = -INFINITY;
        #pragma unroll
        for (int tb = 0; tb < 4; tb++){
            float4 c4 = *(const float4*)&cumL[16*tb + 4*quad];
            float4 g4 = *(const float4*)&igL[16*tb + 4*quad];
            float ccv[4] = {c4.x, c4.y, c4.z, c4.w};
            float gg[4] = {g4.x, g4.y, g4.z, g4.w};
            #pragma unroll
            for (int r = 0; r < 4; r++){
                float d = cq - ccv[r] + gg[r];
                if (diag && (t0 + 16*tb + 4*quad + r) > s_glob) d = -INFINITY;
                dv[tb][r] = d;
                pmax = fmaxf(pmax, d);
            }
        }
        pmax = fmaxf(pmax, __shfl_xor(pmax, 16, 64));
        pmax = fmaxf(pmax, __shfl_xor(pmax, 32, 64));
        float mn = fmaxf(m_s, pmax);
        float sc = exp2f((m_s - mn) * LOG2E);
        m_s = mn;
        float rs = 0.f;
        bf16x4 pf[4];   // P^T in 16x16x16 A-operand layout
        #pragma unroll
        for (int tb = 0; tb < 4; tb++){
            #pragma unroll
            for (int r = 0; r < 4; r++){
                float pv = st4[tb][r] * exp2f((dv[tb][r] - mn) * LOG2E);
                rs += pv;
                pf[tb][r] = (short)f2bf(pv);
            }
        }
        rs += __shfl_xor(rs, 16, 64);
        rs += __shfl_xor(rs, 32, 64);
        b_s = b_s * sc + rs;

        #pragma unroll
        for (int r = 0; r < 4; r++){
            float sco = __shfl(sc, 20*quad + r, 64);
            #pragma unroll
            for (int cg = 0; cg < 4; cg++) oacc[cg][r] *= sco;
        }

        // ---- matmul2: O += P @ V ----
        #pragma unroll
        for (int tb = 0; tb < 4; tb++){
            #pragma unroll
            for (int cg = 0; cg < 4; cg++){
                bf16x4 vf = *(const bf16x4*)&vt[(16*cg + lq)*KSTR + 16*tb + 4*quad];
                oacc[cg] = __builtin_amdgcn_mfma_f32_16x16x16bf16_1k(pf[tb], vf, oacc[cg], 0, 0, 0);
            }
        }
    }

    // ---- write partials ----
    float* po = pO + (size_t)pblk * 4096;
    #pragma unroll
    for (int r = 0; r < 4; r++){
        int row = 16*wv + 4*quad + r;
        #pragma unroll
        for (int cg = 0; cg < 4; cg++)
            po[row*64 + 16*cg + lq] = oacc[cg][r];
    }
    if (quad == 0){
        pM[pblk*64 + 16*wv + lq] = m_s;
        pL[pblk*64 + 16*wv + lq] = b_s;
    }
}

// ---------------- Kernel 3b: combine partials + normalizer + LayerNorm -------
// One block per q-tile; merge <=4 split partials with exp-weights, then
// normalizer + per-head LayerNorm + scale.
__global__ __launch_bounds__(256) void mlstm_combine(
    const float* __restrict__ pO, const float* __restrict__ pM,
    const float* __restrict__ pL, const float* __restrict__ w,
    float* __restrict__ out) {
    int st = blockIdx.x;
    int bh = blockIdx.y;
    int b = bh / NH, h = bh % NH;
    int tid = threadIdx.x;
    int cl = (tid & 15) * 4;       // col base (float4)
    int rb = tid >> 4;             // row within 16-row band

    int pblk[NSPLIT];
    #pragma unroll
    for (int p = 0; p < NSPLIT; p++)
        pblk[p] = (((NT - 1 - st) << 2) + p) * NBH + bh;

    float4 wv4 = *(const float4*)(w + h*DH + cl);

    #pragma unroll
    for (int pass = 0; pass < 4; pass++){
        int row = pass*16 + rb;
        float mp[NSPLIT], lp[NSPLIT];
        float mmax = -INFINITY;
        #pragma unroll
        for (int p = 0; p < NSPLIT; p++){
            mp[p] = pM[pblk[p]*64 + row];
            lp[p] = pL[pblk[p]*64 + row];
            mmax = fmaxf(mmax, mp[p]);
        }
        float l = 0.f;
        float4 o = {0.f, 0.f, 0.f, 0.f};
        #pragma unroll
        for (int p = 0; p < NSPLIT; p++){
            float wp = exp2f((mp[p] - mmax) * LOG2E);   // empty split: 0
            l += wp * lp[p];
            float4 t = *(const float4*)(pO + (size_t)pblk[p]*4096 + row*64 + cl);
            o.x += wp*t.x; o.y += wp*t.y; o.z += wp*t.z; o.w += wp*t.w;
        }
        float nrm = fmaxf(fabsf(l), exp2f(-mmax * LOG2E));
        float inv = 1.f / (nrm + EPS);
        float x[4] = {o.x*inv, o.y*inv, o.z*inv, o.w*inv};
        float s1 = x[0]+x[1]+x[2]+x[3];
        float s2 = x[0]*x[0]+x[1]*x[1]+x[2]*x[2]+x[3]*x[3];
        #pragma unroll
        for (int off = 8; off >= 1; off >>= 1){
            s1 += __shfl_xor(s1, off, 64);
            s2 += __shfl_xor(s2, off, 64);
        }
        float mean = s1 * (1.f/64.f);
        float var  = s2 * (1.f/64.f) - mean*mean;
        float rstd = rsqrtf(var + LN_EPS);
        float4 oo;
        oo.x = (x[0]-mean)*rstd*(1.f + wv4.x);
        oo.y = (x[1]-mean)*rstd*(1.f + wv4.y);
        oo.z = (x[2]-mean)*rstd*(1.f + wv4.z);
        oo.w = (x[3]-mean)*rstd*(1.f + wv4.w);
        *(float4*)(out + ((size_t)b*S_ + st*64 + row)*DIM + h*DH + cl) = oo;
    }
}

extern "C" void kernel_launch(void* const* d_in, const int* in_sizes, int n_in,
                              void* d_out, int out_size, void* d_ws, size_t ws_size,
                              hipStream_t stream) {
    const float* q  = (const float*)d_in[0];
    const float* k  = (const float*)d_in[1];
    const float* v  = (const float*)d_in[2];
    const float* iw = (const float*)d_in[3];
    const float* ib = (const float*)d_in[4];
    const float* fw = (const float*)d_in[5];
    const float* fb = (const float*)d_in[6];
    const float* w  = (const float*)d_in[7];
    float* out = (float*)d_out;

    const int nPart = NBH * NT * NSPLIT;       // 1536
    float* ig  = (float*)d_ws;                 // B*NH*S
    float* lf  = ig  + (size_t)NBH*S_;         // B*NH*S
    float* cum = lf  + (size_t)NBH*S_;         // B*NH*S
    float* pM  = cum + (size_t)NBH*S_;         // nPart*64
    float* pL  = pM  + (size_t)nPart*64;       // nPart*64
    float* pO  = pL  + (size_t)nPart*64;       // nPart*4096  (~25 MB)

    gates_kernel<<<B_*S_/4, 256, 0, stream>>>(q, k, v, iw, ib, fw, fb, ig, lf);
    scan_kernel<<<NBH, 256, 0, stream>>>(lf, cum);
    mlstm_part<<<nPart, 256, 0, stream>>>(q, k, v, ig, cum, pO, pM, pL);
    mlstm_combine<<<dim3(NT, NBH), 256, 0, stream>>>(pO, pM, pL, w, out);
}